// Round 12
// baseline (843.109 us; speedup 1.0000x reference)
//
#include <hip/hip_runtime.h>

// ---------------------------------------------------------------------------
// SelfAttention: B=1024, C=N=256.
//   Q=(WqX+bq)/16 ; K=WkX+bk ; Vg=gamma*(WvX+bv) ; P=softmax_rows(Q K^T);
//   out = Vg P + x
// R12 pipeline:
//   k_prep / k_transpose / k_gemm : unchanged (R11, ~265 us combined)
//   attn7 : quarter-staged K (32KB dbuf, overlapped with QK^T), exp(S) kept
//           in regs, P^T consumed in two 64KB n-halves (Q,K,V each read once),
//           64 KB LDS total.
// ---------------------------------------------------------------------------

typedef __attribute__((ext_vector_type(8))) short bf16x8;
typedef __attribute__((ext_vector_type(4))) short bf16x4;
typedef __attribute__((ext_vector_type(4))) float f32x4;

#define MFMA16(a, b, c) __builtin_amdgcn_mfma_f32_16x16x32_bf16((a), (b), (c), 0, 0, 0)

#define GLDS16(g, l)                                                      \
  __builtin_amdgcn_global_load_lds(                                       \
      (const __attribute__((address_space(1))) void*)(g),                 \
      (__attribute__((address_space(3))) void*)(l), 16, 0, 0)

static __device__ __forceinline__ unsigned short f2bf(float f) {
  unsigned int u = __float_as_uint(f);
  u += 0x7fffu + ((u >> 16) & 1u);  // round-to-nearest-even
  return (unsigned short)(u >> 16);
}

static __device__ __forceinline__ float bf2f(unsigned short s) {
  return __uint_as_float((unsigned int)s << 16);
}

// 512B-row swizzle (K quarters in attn7, gemm tiles)
static __device__ __forceinline__ int swz(int row, int byteInRow) {
  return row * 512 + (byteInRow ^ ((row & 7) << 4));
}
// 256B-row swizzle (P^T halves in attn7)
static __device__ __forceinline__ int swz256(int row, int byteInRow) {
  return row * 256 + (byteInRow ^ ((row & 7) << 4));
}

// ---------------------------------------------------------------------------
// Kernel 0: stacked scaled weights + biases.
// ---------------------------------------------------------------------------
__global__ void k_prep(const float* __restrict__ Wq, const float* __restrict__ bq,
                       const float* __restrict__ Wk, const float* __restrict__ bk,
                       const float* __restrict__ Wv, const float* __restrict__ bv,
                       const float* __restrict__ gamma,
                       unsigned short* __restrict__ W3h, float* __restrict__ b3) {
  const int r = blockIdx.x;  // 0..767
  const int p = r >> 8, sr = r & 255;
  const float s = (p == 0) ? 0.0625f : (p == 1 ? 1.0f : gamma[0]);
  const float* W = (p == 0) ? Wq : (p == 1 ? Wk : Wv);
  const float* bs = (p == 0) ? bq : (p == 1 ? bk : bv);
  W3h[r * 256 + threadIdx.x] = f2bf(W[sr * 256 + threadIdx.x] * s);
  if (threadIdx.x == 0) b3[r] = bs[sr] * s;
}

// ---------------------------------------------------------------------------
// Kernel 1: Xt[b*256 + n][i] = bf16(x[b][i][n])
// ---------------------------------------------------------------------------
__global__ void k_transpose(const float* __restrict__ x, unsigned short* __restrict__ xt) {
  __shared__ float tile[64][65];
  const int b = blockIdx.x;
  const float* xb = x + (size_t)b * 65536;
  unsigned short* xtb = xt + (size_t)b * 65536;
  const int t = threadIdx.x, tx = t & 63, ty = t >> 6;
  const int cp = t & 31, rb = t >> 5;
  for (int tb = 0; tb < 16; ++tb) {
    const int c0 = (tb >> 2) * 64, n0 = (tb & 3) * 64;
    __syncthreads();
#pragma unroll
    for (int yy = 0; yy < 16; ++yy) {
      const int r = ty + yy * 4;
      tile[r][tx] = xb[(c0 + r) * 256 + n0 + tx];
    }
    __syncthreads();
#pragma unroll
    for (int yy = 0; yy < 8; ++yy) {
      const int nl = rb + yy * 8;
      ushort2 v;
      v.x = f2bf(tile[2 * cp][nl]);
      v.y = f2bf(tile[2 * cp + 1][nl]);
      *(ushort2*)(xtb + (n0 + nl) * 256 + c0 + 2 * cp) = v;
    }
  }
}

// ---------------------------------------------------------------------------
// Kernel 2: flat GEMM  Y[.] = W3h * Xt^T + b3, batch-major output.
// ---------------------------------------------------------------------------
__global__ __launch_bounds__(256, 4) void k_gemm(
    const unsigned short* __restrict__ W3h, const float* __restrict__ b3,
    const unsigned short* __restrict__ Xt, unsigned short* __restrict__ Y) {
  __shared__ char smem[32768];
  const int bid = blockIdx.x;
  const int swzb = (bid & 7) * 1536 + (bid >> 3);
  const int r_t = swzb % 6, bn_t = swzb / 6;
  const int m0 = r_t * 128, n0 = bn_t * 128;
  const int tid = threadIdx.x, wv = tid >> 6, lane = tid & 63;
  const int lo = lane & 15, hi = lane >> 4;
  const int wm = wv >> 1, wn = wv & 1;

  f32x4 acc[4][4];
#pragma unroll
  for (int i = 0; i < 4; ++i)
#pragma unroll
    for (int j = 0; j < 4; ++j) acc[i][j] = (f32x4){0.f, 0.f, 0.f, 0.f};

  for (int k0 = 0; k0 < 256; k0 += 64) {
#pragma unroll
    for (int j = 0; j < 4; ++j) {
      const int s = j * 256 + tid;
      const int row = s >> 3, gs = (s & 7) ^ (row & 7);
      GLDS16(W3h + (size_t)(m0 + row) * 256 + k0 + gs * 8,
             smem + j * 4096 + wv * 1024);
    }
#pragma unroll
    for (int j = 0; j < 4; ++j) {
      const int s = j * 256 + tid;
      const int row = s >> 3, gs = (s & 7) ^ (row & 7);
      GLDS16(Xt + (size_t)(n0 + row) * 256 + k0 + gs * 8,
             smem + 16384 + j * 4096 + wv * 1024);
    }
    __syncthreads();
#pragma unroll
    for (int kk = 0; kk < 2; ++kk) {
      bf16x8 a[4], b[4];
#pragma unroll
      for (int rt = 0; rt < 4; ++rt) {
        const int row = wm * 64 + rt * 16 + lo, g = kk * 4 + hi;
        a[rt] = *(const bf16x8*)(smem + row * 128 + ((g ^ (row & 7)) * 16));
      }
#pragma unroll
      for (int ct = 0; ct < 4; ++ct) {
        const int row = wn * 64 + ct * 16 + lo, g = kk * 4 + hi;
        b[ct] = *(const bf16x8*)(smem + 16384 + row * 128 + ((g ^ (row & 7)) * 16));
      }
#pragma unroll
      for (int rt = 0; rt < 4; ++rt)
#pragma unroll
        for (int ct = 0; ct < 4; ++ct) acc[rt][ct] = MFMA16(a[rt], b[ct], acc[rt][ct]);
    }
    __syncthreads();
  }

  float b3v[4][4];
#pragma unroll
  for (int rt = 0; rt < 4; ++rt)
#pragma unroll
    for (int reg = 0; reg < 4; ++reg)
      b3v[rt][reg] = b3[m0 + wm * 64 + rt * 16 + hi * 4 + reg];
#pragma unroll
  for (int rt = 0; rt < 4; ++rt)
#pragma unroll
    for (int ct = 0; ct < 4; ++ct)
#pragma unroll
      for (int reg = 0; reg < 4; ++reg) {
        const int m = wm * 64 + rt * 16 + hi * 4 + reg;
        const int n = wn * 64 + ct * 16 + lo;
        *(unsigned short*)(smem + m * 256 + ((n * 2) ^ ((m & 7) << 4))) =
            f2bf(acc[rt][ct][reg] + b3v[rt][reg]);
      }
  __syncthreads();
  const int p = m0 >> 8, sr0 = m0 & 255;
  const int bb = n0 >> 8, nl0 = n0 & 255;
  unsigned short* dstb = Y + (size_t)bb * 196608 + (size_t)p * 65536;
#pragma unroll
  for (int j = 0; j < 8; ++j) {
    const int s = j * 256 + tid;
    const int m = s >> 4, pp = s & 15;
    const int ng = pp ^ (m & 7);
    int4 v = *(const int4*)(smem + m * 256 + pp * 16);
    *(int4*)(dstb + (size_t)(sr0 + m) * 256 + nl0 + ng * 8) = v;
  }
}

// ---------------------------------------------------------------------------
// Kernel 3: attn7 — quarter-staged K, pk-in-regs, n-halved PV. 64 KB LDS.
// ---------------------------------------------------------------------------
__global__ __launch_bounds__(512, 2) void attn7(
    const float* __restrict__ x, const unsigned short* __restrict__ Y,
    float* __restrict__ out) {
  __shared__ char smem[65536];  // K dbuf: [0,32K)+[32K,64K); later P^T 64KB
  const int b = blockIdx.x;
  const float* xb = x + (size_t)b * 65536;
  const unsigned short* Qb = Y + (size_t)b * 196608;
  const unsigned short* Kb = Qb + 65536;
  const unsigned short* Vb = Qb + 131072;
  const int tid = threadIdx.x, w = tid >> 6, lane = tid & 63;
  const int lo = lane & 15, hi = lane >> 4;
  const int r0 = w * 32;

  // ---- stage one 32KB K-quarter (rows q*64..q*64+63) into region reg ----
#define STAGE_K(q, reg)                                                     \
  {                                                                         \
    _Pragma("unroll") for (int i = 0; i < 4; ++i) {                         \
      const int idx = i * 512 + tid;      /* 0..2047 16B granules */        \
      const int row = idx >> 5, c16 = idx & 31;                             \
      const int gs = (c16 & 24) | ((c16 ^ row) & 7);                        \
      GLDS16(Kb + (size_t)((q) * 64 + row) * 256 + gs * 8,                  \
             smem + (reg) * 32768 + idx * 16);                              \
    }                                                                       \
  }

  STAGE_K(0, 0)
  STAGE_K(1, 1)
  // Q fragments for this wave's 32 rows (read once)
  bf16x8 aq[2][8];
#pragma unroll
  for (int k0 = 0; k0 < 8; ++k0)
#pragma unroll
    for (int rt = 0; rt < 2; ++rt)
      aq[rt][k0] =
          *(const bf16x8*)(Qb + (size_t)(r0 + rt * 16 + lo) * 256 + k0 * 32 + hi * 8);
  __syncthreads();  // K0, K1, Q resident

  bf16x4 pk[4][2][4];  // unnormalized exp(S) bf16, [quarter][rt][ct]
  f32x4 lsum[2];
  lsum[0] = (f32x4){0.f, 0.f, 0.f, 0.f};
  lsum[1] = (f32x4){0.f, 0.f, 0.f, 0.f};

  // ---- one d-quarter of S = Q K^T, exp, pack ----
#define QUARTER(q, reg)                                                     \
  {                                                                         \
    const char* base = smem + (reg) * 32768;                                \
    f32x4 acc[2][4];                                                        \
    _Pragma("unroll") for (int i = 0; i < 2; ++i)                           \
        _Pragma("unroll") for (int j = 0; j < 4; ++j)                       \
            acc[i][j] = (f32x4){0.f, 0.f, 0.f, 0.f};                        \
    _Pragma("unroll") for (int k0 = 0; k0 < 8; ++k0)                        \
        _Pragma("unroll") for (int ct = 0; ct < 4; ++ct) {                  \
      bf16x8 bb = *(const bf16x8*)(base + swz(ct * 16 + lo,                 \
                                              (k0 * 32 + hi * 8) * 2));     \
      acc[0][ct] = MFMA16(aq[0][k0], bb, acc[0][ct]);                       \
      acc[1][ct] = MFMA16(aq[1][k0], bb, acc[1][ct]);                       \
    }                                                                       \
    _Pragma("unroll") for (int rt = 0; rt < 2; ++rt)                        \
        _Pragma("unroll") for (int ct = 0; ct < 4; ++ct) {                  \
      f32x4 p;                                                              \
      _Pragma("unroll") for (int reg2 = 0; reg2 < 4; ++reg2)                \
          p[reg2] = __expf(acc[rt][ct][reg2]);                              \
      lsum[rt] += p;                                                        \
      bf16x4 v;                                                             \
      _Pragma("unroll") for (int reg2 = 0; reg2 < 4; ++reg2)                \
          v[reg2] = (short)f2bf(p[reg2]);                                   \
      pk[q][rt][ct] = v;                                                    \
    }                                                                       \
  }

  QUARTER(0, 0)
  __syncthreads();       // all waves done reading region 0
  STAGE_K(2, 0)          // async; overlaps quarter 1 compute
  QUARTER(1, 1)
  __syncthreads();       // drains K2; region-1 reads done
  STAGE_K(3, 1)          // async; overlaps quarter 2 compute
  QUARTER(2, 0)
  __syncthreads();       // drains K3
  QUARTER(3, 1)

  // ---- row-sum reduce over the 16 lo-lanes; inv = 1/l ----
  f32x4 inv[2];
#pragma unroll
  for (int rt = 0; rt < 2; ++rt)
#pragma unroll
    for (int reg = 0; reg < 4; ++reg) {
      float s = lsum[rt][reg];
      s += __shfl_xor(s, 1);
      s += __shfl_xor(s, 2);
      s += __shfl_xor(s, 4);
      s += __shfl_xor(s, 8);
      inv[rt][reg] = 1.0f / s;
    }
  __syncthreads();  // quarter-3 reads done before P^T overwrite

  // ---- write this wave's pk as P^T[d][n-local] (normalized) ----
#define WRITE_PK                                                            \
  {                                                                         \
    _Pragma("unroll") for (int q = 0; q < 4; ++q)                           \
        _Pragma("unroll") for (int rt = 0; rt < 2; ++rt)                    \
            _Pragma("unroll") for (int ct = 0; ct < 4; ++ct) {              \
      const int d = q * 64 + ct * 16 + lo;                                  \
      const int cl = (w & 3) * 32 + rt * 16 + hi * 4;                       \
      bf16x4 src = pk[q][rt][ct];                                           \
      bf16x4 v;                                                             \
      _Pragma("unroll") for (int reg2 = 0; reg2 < 4; ++reg2)                \
          v[reg2] = (short)f2bf(bf2f((unsigned short)src[reg2]) *           \
                                inv[rt][reg2]);                             \
      *(bf16x4*)(smem + swz256(d, cl * 2)) = v;                             \
    }                                                                       \
  }

  // ---- Phase B: O accumulated over two n-halves; V read once ----
  const int rb0 = (w >> 1) * 64, d0 = (w & 1) * 128;
  f32x4 accB[4][8];
#pragma unroll
  for (int i = 0; i < 4; ++i)
#pragma unroll
    for (int j = 0; j < 8; ++j) accB[i][j] = (f32x4){0.f, 0.f, 0.f, 0.f};

#define PV_HALF(h)                                                          \
  {                                                                         \
    _Pragma("unroll") for (int k0 = 0; k0 < 4; ++k0) {                      \
      bf16x8 a[4];                                                          \
      _Pragma("unroll") for (int rt = 0; rt < 4; ++rt)                      \
          a[rt] = *(const bf16x8*)(Vb + (size_t)(rb0 + rt * 16 + lo) * 256  \
                                   + (h) * 128 + k0 * 32 + hi * 8);         \
      _Pragma("unroll") for (int ct = 0; ct < 8; ++ct) {                    \
        const int row = d0 + ct * 16 + lo;                                  \
        bf16x8 bb = *(const bf16x8*)(smem +                                 \
                                     swz256(row, k0 * 64 + hi * 16));       \
        _Pragma("unroll") for (int rt = 0; rt < 4; ++rt)                    \
            accB[rt][ct] = MFMA16(a[rt], bb, accB[rt][ct]);                 \
      }                                                                     \
    }                                                                       \
  }

  if (w < 4) WRITE_PK
  __syncthreads();
  PV_HALF(0)
  __syncthreads();  // half-0 P^T reads done
  if (w >= 4) WRITE_PK
  __syncthreads();
  PV_HALF(1)

  // ---- epilogue: out = O + x ----
  float* ob = out + (size_t)b * 65536;
#pragma unroll
  for (int rt = 0; rt < 4; ++rt)
#pragma unroll
    for (int reg = 0; reg < 4; ++reg) {
      const int c = rb0 + rt * 16 + hi * 4 + reg;
#pragma unroll
      for (int ct = 0; ct < 8; ++ct) {
        const int d = d0 + ct * 16 + lo;
        const int idx = c * 256 + d;
        ob[idx] = accB[rt][ct][reg] + xb[idx];
      }
    }
}

// ---------------------------------------------------------------------------
extern "C" void kernel_launch(void* const* d_in, const int* in_sizes, int n_in,
                              void* d_out, int out_size, void* d_ws, size_t ws_size,
                              hipStream_t stream) {
  const float* x = (const float*)d_in[0];
  const float* Wq = (const float*)d_in[1];
  const float* bq = (const float*)d_in[2];
  const float* Wk = (const float*)d_in[3];
  const float* bk = (const float*)d_in[4];
  const float* Wv = (const float*)d_in[5];
  const float* bv = (const float*)d_in[6];
  const float* gamma = (const float*)d_in[7];
  float* out = (float*)d_out;

  unsigned short* Y = (unsigned short*)d_ws;                 // 384 MiB
  unsigned short* Xt = Y + (size_t)1024 * 196608;            // 128 MiB
  unsigned short* W3h = Xt + (size_t)1024 * 65536;           // 384 KiB
  float* b3 = (float*)(W3h + 768 * 256);                     // 3 KiB
  const size_t need = ((size_t)1024 * 196608 + (size_t)1024 * 65536 + 768 * 256) * 2 + 768 * 4;
  if (ws_size < need) return;

  hipLaunchKernelGGL(k_prep, dim3(768), dim3(256), 0, stream,
                     Wq, bq, Wk, bk, Wv, bv, gamma, W3h, b3);
  hipLaunchKernelGGL(k_transpose, dim3(1024), dim3(256), 0, stream, x, Xt);
  hipLaunchKernelGGL(k_gemm, dim3(12288), dim3(256), 0, stream, W3h, b3, Xt, Y);
  hipLaunchKernelGGL(attn7, dim3(1024), dim3(512), 0, stream, x, Y, out);
}